// Round 7
// baseline (342.502 us; speedup 1.0000x reference)
//
#include <hip/hip_runtime.h>

#define B_ROWS 14336
#define D_DIM  512
#define C_CLS  7
#define M_CLS  2048

typedef __attribute__((ext_vector_type(8))) short bf16x8;
typedef __attribute__((ext_vector_type(4))) float f32x4;

__device__ __forceinline__ short bf16_rne(float x) {
  unsigned u = __float_as_uint(x);
  u += 0x7fffu + ((u >> 16) & 1u);
  return (short)(u >> 16);
}

// K0: fea->bf16 + row norms + logits + zero small accumulators.
__global__ __launch_bounds__(256) void k_prep(const float* __restrict__ fea,
                                              const float* __restrict__ W,
                                              short* __restrict__ fb,
                                              float* __restrict__ an,
                                              float* __restrict__ logits,
                                              float* __restrict__ zb) {  // 64 floats: S1,S2,S
  int t = threadIdx.x;
  if (blockIdx.x == 0 && t < 64) zb[t] = 0.f;

  int wave = t >> 6, lane = t & 63;
  int gw = blockIdx.x * 4 + wave;
  for (int it = 0; it < 8; ++it) {
    int row = gw + it * 1792;
    const float4* fr4 = (const float4*)(fea + (size_t)row * D_DIM);
    float4 v0 = fr4[lane * 2], v1 = fr4[lane * 2 + 1];
    float s = v0.x * v0.x + v0.y * v0.y + v0.z * v0.z + v0.w * v0.w +
              v1.x * v1.x + v1.y * v1.y + v1.z * v1.z + v1.w * v1.w;
#pragma unroll
    for (int o = 1; o < 64; o <<= 1) s += __shfl_xor(s, o);
    if (lane == 0) an[row] = s;
    int4 pk;
    pk.x = (unsigned short)bf16_rne(v0.x) | ((unsigned)(unsigned short)bf16_rne(v0.y) << 16);
    pk.y = (unsigned short)bf16_rne(v0.z) | ((unsigned)(unsigned short)bf16_rne(v0.w) << 16);
    pk.z = (unsigned short)bf16_rne(v1.x) | ((unsigned)(unsigned short)bf16_rne(v1.y) << 16);
    pk.w = (unsigned short)bf16_rne(v1.z) | ((unsigned)(unsigned short)bf16_rne(v1.w) << 16);
    ((int4*)(fb + (size_t)row * D_DIM))[lane] = pk;
#pragma unroll
    for (int c = 0; c < 7; ++c) {
      const float4* w4 = (const float4*)(W + c * D_DIM);
      float4 w0 = w4[lane * 2], w1 = w4[lane * 2 + 1];
      float p = v0.x * w0.x + v0.y * w0.y + v0.z * w0.z + v0.w * w0.w +
                v1.x * w1.x + v1.y * w1.y + v1.z * w1.z + v1.w * w1.w;
#pragma unroll
      for (int o = 1; o < 64; o <<= 1) p += __shfl_xor(p, o);
      if (lane == 0) logits[row * 7 + c] = p;
    }
  }
}

// K1: fused Gram + exp reductions. 128x128 tile, BK=64, r5's proven-conflict-free
// XOR-swizzled LDS layout, but staging via buffer_load->regs + ds_write_b128
// (AITER-style): vmem waits are PER-WAVE (before own ds_write), never a
// block-wide barrier drain. Loads for kt+1 are issued at the top of compute kt.
__global__ __launch_bounds__(256, 3) void k_gram(const short* __restrict__ fb,
                                                 const float* __restrict__ an,
                                                 const float* __restrict__ logits,
                                                 float* __restrict__ S,
                                                 float* __restrict__ rs_part,
                                                 float* __restrict__ S1,
                                                 float* __restrict__ S2) {
  int unit = blockIdx.x >> 3, xcd = blockIdx.x & 7;
  int t = threadIdx.x, lane = t & 63, wave = t >> 6;

  if (unit >= 311) {  // batch-norm stats partials
    int sidx = (unit - 311) * 8 + xcd;  // 0..55
    int c = sidx >> 3, chunk = sidx & 7;
    int r0 = chunk * 1792;
    float s1 = 0.f, s2 = 0.f;
    for (int j = t; j < 1792; j += 256) {
      float v = logits[(r0 + j) * 7 + c];
      s1 += v;
      s2 += v * v;
    }
#pragma unroll
    for (int o = 1; o < 64; o <<= 1) {
      s1 += __shfl_xor(s1, o);
      s2 += __shfl_xor(s2, o);
    }
    __shared__ float r1_[4], r2_[4];
    if (lane == 0) { r1_[wave] = s1; r2_[wave] = s2; }
    __syncthreads();
    if (t == 0) {
      atomicAdd(&S1[c], r1_[0] + r1_[1] + r1_[2] + r1_[3]);
      atomicAdd(&S2[c], r2_[0] + r2_[1] + r2_[2] + r2_[3]);
    }
    return;
  }

  int c1, c2, TI, TJ, Sidx;
  bool self;
  if (xcd < 7 && unit < 136) {
    int tj = 0, t2 = unit;
    while (t2 > tj) { t2 -= (tj + 1); ++tj; }  // idx = tj*(tj+1)/2 + ti, ti<=tj
    TI = t2; TJ = tj;
    c1 = xcd; c2 = xcd; Sidx = xcd; self = true;
  } else {
    int e = (xcd < 7) ? (xcd * 175 + unit - 136) : (1225 + unit);
    int p = e >> 8;
    int tl = e & 255;
    TJ = tl >> 4; TI = tl & 15;
    c1 = p + 1; c2 = 0; Sidx = 7 + p; self = false;
  }
  bool diag = self && (TI == TJ);
  bool off  = self && (TI < TJ);
  int rowA0 = c1 * M_CLS + TI * 128;
  int rowB0 = c2 * M_CLS + TJ * 128;

  __shared__ short lA[128 * 64];   // 16 KB, rows of 64 shorts (128 B) as in r5
  __shared__ short lB[128 * 64];

  f32x4 acc[4][4];
#pragma unroll
  for (int i = 0; i < 4; ++i)
#pragma unroll
    for (int j = 0; j < 4; ++j)
      acc[i][j] = (f32x4){0.f, 0.f, 0.f, 0.f};

  int wr = wave >> 1, wc = wave & 1;  // 2x2 waves of 64x64
  int q = lane >> 4, s = lane & 15;

  // frag-read physical segs (r5 swizzle, measured 0 conflicts)
  int ps0 = q ^ (s & 7);
  int ps1 = (4 + q) ^ (s & 7);

  // --- staging geometry: per thread, 4 A rows + 4 B rows, one int4 each ---
  // thread -> (row = wave*32 + c*8 + (lane>>3), phys seg = lane&7)
  // source seg = physseg ^ (row & 7)  [bijective row swizzle, as r5 DMA]
  int j8 = lane >> 3, seg = lane & 7;
  int srcOff[4], dstOff[4];
#pragma unroll
  for (int c = 0; c < 4; ++c) {
    int row = wave * 32 + c * 8 + j8;
    srcOff[c] = row * D_DIM + (seg ^ (row & 7)) * 8;  // + k0
    dstOff[c] = row * 64 + seg * 8;                   // phys seg = seg
  }
  const short* pA = fb + (size_t)rowA0 * D_DIM;
  const short* pB = fb + (size_t)rowB0 * D_DIM;

  int4 ra[4], rb[4];
#define LOADS(k0_)                                                   \
  do {                                                               \
    _Pragma("unroll") for (int c = 0; c < 4; ++c) {                  \
      ra[c] = *(const int4*)(pA + srcOff[c] + (k0_));                \
      if (!diag) rb[c] = *(const int4*)(pB + srcOff[c] + (k0_));     \
    }                                                                \
  } while (0)

  LOADS(0);
  for (int kt = 0; kt < 8; ++kt) {
    if (kt) __syncthreads();  // readers of previous tile done; drains this kt's loads (needed now)
#pragma unroll
    for (int c = 0; c < 4; ++c) {
      *(int4*)&lA[dstOff[c]] = ra[c];
      if (!diag) *(int4*)&lB[dstOff[c]] = rb[c];
    }
    __syncthreads();          // LDS-only drain: no vmem outstanding here
    if (kt < 7) LOADS((kt + 1) * 64);  // fly during compute of kt
    const short* Bp = diag ? lA : lB;
#pragma unroll
    for (int kk = 0; kk < 64; kk += 32) {
      int ps = (kk == 0) ? ps0 : ps1;
      bf16x8 af[4], bfv[4];
#pragma unroll
      for (int mi = 0; mi < 4; ++mi)
        af[mi] = *(const bf16x8*)&lA[(wr * 64 + mi * 16 + s) * 64 + ps * 8];
#pragma unroll
      for (int mj = 0; mj < 4; ++mj)
        bfv[mj] = *(const bf16x8*)&Bp[(wc * 64 + mj * 16 + s) * 64 + ps * 8];
#pragma unroll
      for (int mi = 0; mi < 4; ++mi)
#pragma unroll
        for (int mj = 0; mj < 4; ++mj)
          acc[mi][mj] = __builtin_amdgcn_mfma_f32_16x16x32_bf16(
              af[mi], bfv[mj], acc[mi][mj], 0, 0, 0);
    }
  }
#undef LOADS

  // row norms into registers (L2-hot)
  float anA[4][4], anB[4];
#pragma unroll
  for (int mi = 0; mi < 4; ++mi)
#pragma unroll
    for (int rg = 0; rg < 4; ++rg)
      anA[mi][rg] = an[rowA0 + wr * 64 + mi * 16 + q * 4 + rg];
#pragma unroll
  for (int mj = 0; mj < 4; ++mj)
    anB[mj] = an[rowB0 + wc * 64 + mj * 16 + s];

  // Epilogue. C/D layout (16x16x32): col = lane&15, row = (lane>>4)*4 + reg.
  // 5-kernel sum via exp-squaring from e1 = exp(-0.05*d2).
  float blockAcc = 0.f;
  float colAcc[4] = {0.f, 0.f, 0.f, 0.f};
  float* dirP = rs_part + (size_t)(TJ * 2 + wc) * 14336 + rowA0;
#pragma unroll
  for (int mi = 0; mi < 4; ++mi) {
#pragma unroll
    for (int rg = 0; rg < 4; ++rg) {
      int rl = wr * 64 + mi * 16 + q * 4 + rg;
      float aA = anA[mi][rg];
      float rowAcc = 0.f;
#pragma unroll
      for (int mj = 0; mj < 4; ++mj) {
        int cl = wc * 64 + mj * 16 + s;
        float g = acc[mi][mj][rg];
        float d2 = fmaxf(aA + anB[mj] - 2.f * g, 0.f);
        if (diag && rl == cl) d2 = 0.f;  // exact diagonal
        float e1 = __expf(-0.05f * d2);
        float e2 = e1 * e1, e4 = e2 * e2, e8 = e4 * e4, e16 = e8 * e8;
        blockAcc += e1 + e2 + e4 + e8 + e16;
        if (self) {
          float ek = __expf(-12.5f * d2);  // KDE: 1/(2*0.2^2)
          rowAcc += ek;
          if (off) colAcc[mj] += ek;
        }
      }
      if (self) {
        rowAcc += __shfl_xor(rowAcc, 1);
        rowAcc += __shfl_xor(rowAcc, 2);
        rowAcc += __shfl_xor(rowAcc, 4);
        rowAcc += __shfl_xor(rowAcc, 8);
        if (s == 0) dirP[rl] = rowAcc;
      }
    }
  }
  if (off) {
    float* mirP = rs_part + (size_t)(TI * 2 + wr) * 14336 + rowB0;
#pragma unroll
    for (int mj = 0; mj < 4; ++mj) {
      float v = colAcc[mj];
      v += __shfl_xor(v, 16);
      v += __shfl_xor(v, 32);
      if (q == 0) mirP[wc * 64 + mj * 16 + s] = v;
    }
    blockAcc *= 2.f;  // mirror tile counted once
  }
#pragma unroll
  for (int o = 1; o < 64; o <<= 1) blockAcc += __shfl_xor(blockAcc, o);
  if (lane == 0) atomicAdd(&S[Sidx], blockAcc);
}

// K2: bnout (blocks 0..391) + KDE weight per class (blocks 392..398).
__global__ __launch_bounds__(256) void k_final(const float* __restrict__ logits,
                                               const float* __restrict__ S1,
                                               const float* __restrict__ S2,
                                               const float* __restrict__ gamma,
                                               const float* __restrict__ beta,
                                               const float* __restrict__ rs_part,
                                               float* __restrict__ wcl,
                                               float* __restrict__ out) {
  int b = blockIdx.x, t = threadIdx.x;
  if (b < 392) {
    int idx = b * 256 + t;  // 392*256 = 100352 exactly
    int row = idx / 7;
    int c = idx - row * 7;
    float mu = S1[c] * (1.f / 14336.f);
    float var = S2[c] * (1.f / 14336.f) - mu * mu;
    out[idx] = gamma[c] * (logits[idx] - mu) * rsqrtf(var + 1e-5f) + beta[c];
    return;
  }
  int c = b - 392;
  // log_norm = -256*ln(2*pi*0.04) - ln(2048)
  const float LOG_NORM = 345.9110632f;
  float v = 0.f;
  for (int i = t; i < M_CLS; i += 256) {
    int row = c * M_CLS + i;
    float rsum = 0.f;
#pragma unroll
    for (int jj = 0; jj < 32; ++jj) rsum += rs_part[jj * 14336 + row];
    v += 1.f / (logf(rsum) + LOG_NORM);
  }
#pragma unroll
  for (int o = 1; o < 64; o <<= 1) v += __shfl_xor(v, o);
  __shared__ float r[4];
  if ((t & 63) == 0) r[t >> 6] = v;
  __syncthreads();
  if (t == 0) wcl[c] = 1.f / ((r[0] + r[1] + r[2] + r[3]) + 1e-5f);
}

// K3: final affinity loss (tiny).
__global__ void k_aff(const float* __restrict__ S, const float* __restrict__ wcl,
                      float* __restrict__ aff_out) {
  if (threadIdx.x == 0) {
    const float inv_m2 = 1.0f / ((float)M_CLS * (float)M_CLS);
    float aff = 0.f;
#pragma unroll
    for (int i = 0; i < 7; ++i) {
      float Ssrc = S[i];
      float Stgt = (i > 0) ? S[0] : S[1];
      float X    = (i > 0) ? S[6 + i] : S[7];  // cross Sidx 7+p is (p+1,0); X01==X10
      aff -= (Ssrc + Stgt - 2.f * X) * inv_m2 * wcl[i];
    }
    aff_out[0] = aff;
  }
}

extern "C" void kernel_launch(void* const* d_in, const int* in_sizes, int n_in,
                              void* d_out, int out_size, void* d_ws, size_t ws_size,
                              hipStream_t stream) {
  const float* fea   = (const float*)d_in[0];
  const float* W_fc  = (const float*)d_in[1];
  const float* gamma = (const float*)d_in[2];
  const float* beta  = (const float*)d_in[3];
  float* out = (float*)d_out;

  char* ws = (char*)d_ws;
  short* fb = (short*)ws;                        // bf16 fea: 14,680,064 B
  float* fbase   = (float*)(ws + 14680064);
  float* an      = fbase;                        // 14336
  float* logits  = fbase + 14336;                // 100352
  float* zb      = fbase + 114688;               // 64-float zero block
  float* S1      = zb;                           //   [0..6]
  float* S2      = zb + 7;                       //   [7..13]
  float* S       = zb + 16;                      //   [16..28] (13 used)
  float* wcl     = fbase + 114752;               // 7 (pad to 8)
  float* rs_part = fbase + 114760;               // 32*14336 = 458752 (fully written)

  k_prep <<<448,  256, 0, stream>>>(fea, W_fc, fb, an, logits, zb);
  k_gram <<<2544, 256, 0, stream>>>(fb, an, logits, S, rs_part, S1, S2);
  k_final<<<399,  256, 0, stream>>>(logits, S1, S2, gamma, beta, rs_part, wcl, out);
  k_aff  <<<1,    64,  0, stream>>>(S, wcl, out + 100352);
}

// Round 8
// 278.753 us; speedup vs baseline: 1.2287x; 1.2287x over previous
//
#include <hip/hip_runtime.h>

#define B_ROWS 14336
#define D_DIM  512
#define C_CLS  7
#define M_CLS  2048

typedef __attribute__((ext_vector_type(8))) short bf16x8;
typedef __attribute__((ext_vector_type(4))) float f32x4;

__device__ __forceinline__ short bf16_rne(float x) {
  unsigned u = __float_as_uint(x);
  u += 0x7fffu + ((u >> 16) & 1u);
  return (short)(u >> 16);
}

// K0: fea->bf16 FRAGMENT-PACKED + row norms + logits + zero accumulators.
// Packed layout (16B units): P[g][j][s], g=row/16, s=row%16, j=k/8 (0..63).
// Flat16B = g*1024 + j*16 + s. A wave MFMA-fragment load for (g, kq) is then
// lanes l=q*16+s reading Flat16B = g*1024 + kq*64 + l -> ONE coalesced 1KB load.
// 448 blocks x 32 contiguous rows (2 groups); transpose via LDS.
__global__ __launch_bounds__(256) void k_prep(const float* __restrict__ fea,
                                              const float* __restrict__ W,
                                              short* __restrict__ fbp,
                                              float* __restrict__ an,
                                              float* __restrict__ logits,
                                              float* __restrict__ zb,   // 64 floats: S1,S2,S
                                              float* __restrict__ aff_out) {
  int t = threadIdx.x, wave = t >> 6, lane = t & 63;
  if (blockIdx.x == 0) {
    if (t < 64) zb[t] = 0.f;
    if (t == 64) aff_out[0] = 0.f;
  }
  __shared__ short lt[32 * 65 * 8];  // 32 rows x 65 16B-chunks (pad +1) = 33,280 B

  int r0 = blockIdx.x * 32;
#pragma unroll
  for (int k = 0; k < 8; ++k) {
    int rl = wave * 8 + k;
    int row = r0 + rl;
    const float4* fr4 = (const float4*)(fea + (size_t)row * D_DIM);
    float4 v0 = fr4[lane * 2], v1 = fr4[lane * 2 + 1];
    float s = v0.x * v0.x + v0.y * v0.y + v0.z * v0.z + v0.w * v0.w +
              v1.x * v1.x + v1.y * v1.y + v1.z * v1.z + v1.w * v1.w;
#pragma unroll
    for (int o = 1; o < 64; o <<= 1) s += __shfl_xor(s, o);
    if (lane == 0) an[row] = s;
    int4 pk;
    pk.x = (unsigned short)bf16_rne(v0.x) | ((unsigned)(unsigned short)bf16_rne(v0.y) << 16);
    pk.y = (unsigned short)bf16_rne(v0.z) | ((unsigned)(unsigned short)bf16_rne(v0.w) << 16);
    pk.z = (unsigned short)bf16_rne(v1.x) | ((unsigned)(unsigned short)bf16_rne(v1.y) << 16);
    pk.w = (unsigned short)bf16_rne(v1.z) | ((unsigned)(unsigned short)bf16_rne(v1.w) << 16);
    *(int4*)&lt[(rl * 65 + lane) * 8] = pk;
#pragma unroll
    for (int c = 0; c < 7; ++c) {
      const float4* w4 = (const float4*)(W + c * D_DIM);
      float4 w0 = w4[lane * 2], w1 = w4[lane * 2 + 1];
      float p = v0.x * w0.x + v0.y * w0.y + v0.z * w0.z + v0.w * w0.w +
                v1.x * w1.x + v1.y * w1.y + v1.z * w1.z + v1.w * w1.w;
#pragma unroll
      for (int o = 1; o < 64; o <<= 1) p += __shfl_xor(p, o);
      if (lane == 0) logits[row * 7 + c] = p;
    }
  }
  __syncthreads();
  // packed write-out: 2048 chunks/block, thread t writes chunks t+p*256 ->
  // out16B = bid*2048 + c  (fully coalesced dwordx4 stores)
  const int4* ls = (const int4*)lt;
  int4* outp = (int4*)fbp + (size_t)blockIdx.x * 2048;
#pragma unroll
  for (int p = 0; p < 8; ++p) {
    int c = p * 256 + t;
    int gl = c >> 10, j = (c >> 4) & 63, s = c & 15;
    outp[c] = ls[(gl * 16 + s) * 65 + j];  // 2-way bank alias only (free)
  }
}

// K1: fused Gram + exp reductions, BARRIER-FREE register-direct MFMA from the
// fragment-packed fbp. 128x128 tile, 2x2 waves of 64x64; per kq-step: 8
// coalesced 1KB wave-loads + 16 MFMA, register double-buffered (depth 1).
// XCD-aware grid + atomic-free rowsum partials (r5). Stats blocks appended.
__global__ __launch_bounds__(256, 2) void k_gram(const short* __restrict__ fbp,
                                                 const float* __restrict__ an,
                                                 const float* __restrict__ logits,
                                                 float* __restrict__ S,
                                                 float* __restrict__ rs_part,
                                                 float* __restrict__ S1,
                                                 float* __restrict__ S2) {
  int unit = blockIdx.x >> 3, xcd = blockIdx.x & 7;
  int t = threadIdx.x, lane = t & 63, wave = t >> 6;

  if (unit >= 311) {  // batch-norm stats partials
    int sidx = (unit - 311) * 8 + xcd;  // 0..55
    int c = sidx >> 3, chunk = sidx & 7;
    int r0 = chunk * 1792;
    float s1 = 0.f, s2 = 0.f;
    for (int j = t; j < 1792; j += 256) {
      float v = logits[(r0 + j) * 7 + c];
      s1 += v;
      s2 += v * v;
    }
#pragma unroll
    for (int o = 1; o < 64; o <<= 1) {
      s1 += __shfl_xor(s1, o);
      s2 += __shfl_xor(s2, o);
    }
    __shared__ float r1_[4], r2_[4];
    if (lane == 0) { r1_[wave] = s1; r2_[wave] = s2; }
    __syncthreads();
    if (t == 0) {
      atomicAdd(&S1[c], r1_[0] + r1_[1] + r1_[2] + r1_[3]);
      atomicAdd(&S2[c], r2_[0] + r2_[1] + r2_[2] + r2_[3]);
    }
    return;
  }

  int c1, c2, TI, TJ, Sidx;
  bool self;
  if (xcd < 7 && unit < 136) {
    int tj = 0, t2 = unit;
    while (t2 > tj) { t2 -= (tj + 1); ++tj; }  // idx = tj*(tj+1)/2 + ti, ti<=tj
    TI = t2; TJ = tj;
    c1 = xcd; c2 = xcd; Sidx = xcd; self = true;
  } else {
    int e = (xcd < 7) ? (xcd * 175 + unit - 136) : (1225 + unit);
    int p = e >> 8;
    int tl = e & 255;
    TJ = tl >> 4; TI = tl & 15;
    c1 = p + 1; c2 = 0; Sidx = 7 + p; self = false;
  }
  bool diag = self && (TI == TJ);
  bool off  = self && (TI < TJ);
  int rowA0 = c1 * M_CLS + TI * 128;
  int rowB0 = c2 * M_CLS + TJ * 128;

  int wr = wave >> 1, wc = wave & 1;  // 2x2 waves of 64x64
  int q = lane >> 4, s = lane & 15;

  // fragment base offsets in shorts: group g at g*8192; lane at lane*8; kq at kq*512
  int gA = (rowA0 >> 4) + wr * 4;
  int gB = (rowB0 >> 4) + wc * 4;
  int oA[4], oB[4];
#pragma unroll
  for (int m = 0; m < 4; ++m) {
    oA[m] = (gA + m) * 8192 + lane * 8;
    oB[m] = (gB + m) * 8192 + lane * 8;  // diag: == oA (loads L1-hit)
  }

  f32x4 acc[4][4];
#pragma unroll
  for (int i = 0; i < 4; ++i)
#pragma unroll
    for (int j = 0; j < 4; ++j)
      acc[i][j] = (f32x4){0.f, 0.f, 0.f, 0.f};

  bf16x8 fa[2][4], fbv[2][4];
#define LD(buf_, kq_)                                                     \
  do {                                                                    \
    _Pragma("unroll") for (int m = 0; m < 4; ++m) {                       \
      fa[buf_][m]  = *(const bf16x8*)(fbp + oA[m] + (kq_) * 512);         \
      fbv[buf_][m] = *(const bf16x8*)(fbp + oB[m] + (kq_) * 512);         \
    }                                                                     \
  } while (0)

  LD(0, 0);
#pragma unroll
  for (int kq = 0; kq < 16; ++kq) {
    int cur = kq & 1;
    if (kq < 15) LD(cur ^ 1, kq + 1);
#pragma unroll
    for (int mi = 0; mi < 4; ++mi)
#pragma unroll
      for (int mj = 0; mj < 4; ++mj)
        acc[mi][mj] = __builtin_amdgcn_mfma_f32_16x16x32_bf16(
            fa[cur][mi], fbv[cur][mj], acc[mi][mj], 0, 0, 0);
  }
#undef LD

  // row norms into registers (L2-hot)
  float anA[4][4], anB[4];
#pragma unroll
  for (int mi = 0; mi < 4; ++mi)
#pragma unroll
    for (int rg = 0; rg < 4; ++rg)
      anA[mi][rg] = an[rowA0 + wr * 64 + mi * 16 + q * 4 + rg];
#pragma unroll
  for (int mj = 0; mj < 4; ++mj)
    anB[mj] = an[rowB0 + wc * 64 + mj * 16 + s];

  // Epilogue. C/D layout (16x16x32): col = lane&15, row = (lane>>4)*4 + reg.
  // 5-kernel sum via exp-squaring from e1 = exp(-0.05*d2).
  float blockAcc = 0.f;
  float colAcc[4] = {0.f, 0.f, 0.f, 0.f};
  float* dirP = rs_part + (size_t)(TJ * 2 + wc) * 14336 + rowA0;
#pragma unroll
  for (int mi = 0; mi < 4; ++mi) {
#pragma unroll
    for (int rg = 0; rg < 4; ++rg) {
      int rl = wr * 64 + mi * 16 + q * 4 + rg;
      float aA = anA[mi][rg];
      float rowAcc = 0.f;
#pragma unroll
      for (int mj = 0; mj < 4; ++mj) {
        int cl = wc * 64 + mj * 16 + s;
        float g = acc[mi][mj][rg];
        float d2 = fmaxf(aA + anB[mj] - 2.f * g, 0.f);
        if (diag && rl == cl) d2 = 0.f;  // exact diagonal
        float e1 = __expf(-0.05f * d2);
        float e2 = e1 * e1, e4 = e2 * e2, e8 = e4 * e4, e16 = e8 * e8;
        blockAcc += e1 + e2 + e4 + e8 + e16;
        if (self) {
          float ek = __expf(-12.5f * d2);  // KDE: 1/(2*0.2^2)
          rowAcc += ek;
          if (off) colAcc[mj] += ek;
        }
      }
      if (self) {
        rowAcc += __shfl_xor(rowAcc, 1);
        rowAcc += __shfl_xor(rowAcc, 2);
        rowAcc += __shfl_xor(rowAcc, 4);
        rowAcc += __shfl_xor(rowAcc, 8);
        if (s == 0) dirP[rl] = rowAcc;
      }
    }
  }
  if (off) {
    float* mirP = rs_part + (size_t)(TI * 2 + wr) * 14336 + rowB0;
#pragma unroll
    for (int mj = 0; mj < 4; ++mj) {
      float v = colAcc[mj];
      v += __shfl_xor(v, 16);
      v += __shfl_xor(v, 32);
      if (q == 0) mirP[wc * 64 + mj * 16 + s] = v;
    }
    blockAcc *= 2.f;  // mirror tile counted once
  }
#pragma unroll
  for (int o = 1; o < 64; o <<= 1) blockAcc += __shfl_xor(blockAcc, o);
  if (lane == 0) atomicAdd(&S[Sidx], blockAcc);
}

// K2: bnout (blocks 0..391) + per-class KDE weight & affinity term (392..398).
// aff_out zeroed in k_prep; each class block atomicAdds its -w_c * mmd_c.
__global__ __launch_bounds__(256) void k_final(const float* __restrict__ logits,
                                               const float* __restrict__ S1,
                                               const float* __restrict__ S2,
                                               const float* __restrict__ gamma,
                                               const float* __restrict__ beta,
                                               const float* __restrict__ rs_part,
                                               const float* __restrict__ S,
                                               float* __restrict__ out) {
  int b = blockIdx.x, t = threadIdx.x;
  if (b < 392) {
    int idx = b * 256 + t;  // 392*256 = 100352 exactly
    int row = idx / 7;
    int c = idx - row * 7;
    float mu = S1[c] * (1.f / 14336.f);
    float var = S2[c] * (1.f / 14336.f) - mu * mu;
    out[idx] = gamma[c] * (logits[idx] - mu) * rsqrtf(var + 1e-5f) + beta[c];
    return;
  }
  int c = b - 392;
  // log_norm = -256*ln(2*pi*0.04) - ln(2048)
  const float LOG_NORM = 345.9110632f;
  float v = 0.f;
  for (int i = t; i < M_CLS; i += 256) {
    int row = c * M_CLS + i;
    float rsum = 0.f;
#pragma unroll
    for (int jj = 0; jj < 32; ++jj) rsum += rs_part[jj * 14336 + row];
    v += 1.f / (logf(rsum) + LOG_NORM);
  }
#pragma unroll
  for (int o = 1; o < 64; o <<= 1) v += __shfl_xor(v, o);
  __shared__ float r[4];
  if ((t & 63) == 0) r[t >> 6] = v;
  __syncthreads();
  if (t == 0) {
    float w = 1.f / ((r[0] + r[1] + r[2] + r[3]) + 1e-5f);
    const float inv_m2 = 1.0f / ((float)M_CLS * (float)M_CLS);
    float Ssrc = S[c];
    float Stgt = (c > 0) ? S[0] : S[1];
    float X    = (c > 0) ? S[6 + c] : S[7];  // cross Sidx 7+p is (p+1,0); X01==X10
    float mmd = (Ssrc + Stgt - 2.f * X) * inv_m2;
    atomicAdd(&out[100352], -mmd * w);
  }
}

extern "C" void kernel_launch(void* const* d_in, const int* in_sizes, int n_in,
                              void* d_out, int out_size, void* d_ws, size_t ws_size,
                              hipStream_t stream) {
  const float* fea   = (const float*)d_in[0];
  const float* W_fc  = (const float*)d_in[1];
  const float* gamma = (const float*)d_in[2];
  const float* beta  = (const float*)d_in[3];
  float* out = (float*)d_out;

  char* ws = (char*)d_ws;
  short* fbp = (short*)ws;                       // packed bf16 fea: 14,680,064 B
  float* fbase   = (float*)(ws + 14680064);
  float* an      = fbase;                        // 14336
  float* logits  = fbase + 14336;                // 100352
  float* zb      = fbase + 114688;               // 64-float zero block
  float* S1      = zb;                           //   [0..6]
  float* S2      = zb + 7;                       //   [7..13]
  float* S       = zb + 16;                      //   [16..28] (13 used)
  float* rs_part = fbase + 114752;               // 32*14336 = 458752 (fully written)

  k_prep <<<448,  256, 0, stream>>>(fea, W_fc, fbp, an, logits, zb, out + 100352);
  k_gram <<<2544, 256, 0, stream>>>(fbp, an, logits, S, rs_part, S1, S2);
  k_final<<<399,  256, 0, stream>>>(logits, S1, S2, gamma, beta, rs_part, S, out);
}

// Round 9
// 253.894 us; speedup vs baseline: 1.3490x; 1.0979x over previous
//
#include <hip/hip_runtime.h>

#define B_ROWS 14336
#define D_DIM  512
#define C_CLS  7
#define M_CLS  2048

typedef __attribute__((ext_vector_type(4))) float f32x4;

// fp8 scale: fea*64 -> sigma~3.2 in e4m3 range; Gram scaled by 4096
#define FP8_SCALE 64.0f
#define INV_2S2   (2.0f / 4096.0f)

// K0: fea->fp8 FRAGMENT-PACKED + row norms (fp32-exact) + logits + zeroing.
// Packed 16B units: flat = g*512 + p*64 + lane, g=row/16, p=k/64, lane=q*16+s.
// Lane's 16B = [k = p*64+q*8 .. +7][k = p*64+32+q*8 .. +7] of row s
// -> one coalesced 1KB wave-load yields TWO K-32 MFMA fragments.
__global__ __launch_bounds__(256) void k_prep(const float* __restrict__ fea,
                                              const float* __restrict__ W,
                                              char* __restrict__ f8p,
                                              float* __restrict__ an,
                                              float* __restrict__ logits,
                                              float* __restrict__ zb,   // 64 floats: S1,S2,S
                                              float* __restrict__ aff_out) {
  int t = threadIdx.x, wave = t >> 6, lane = t & 63;
  if (blockIdx.x == 0) {
    if (t < 64) zb[t] = 0.f;
    if (t == 64) aff_out[0] = 0.f;
  }
  __shared__ char lrow[32 * 528];  // 32 rows x 512B fp8 (+16 pad)

  int r0 = blockIdx.x * 32;
#pragma unroll
  for (int k = 0; k < 8; ++k) {
    int rl = wave * 8 + k;
    int row = r0 + rl;
    const float4* fr4 = (const float4*)(fea + (size_t)row * D_DIM);
    float4 v0 = fr4[lane * 2], v1 = fr4[lane * 2 + 1];
    float s = v0.x * v0.x + v0.y * v0.y + v0.z * v0.z + v0.w * v0.w +
              v1.x * v1.x + v1.y * v1.y + v1.z * v1.z + v1.w * v1.w;
#pragma unroll
    for (int o = 1; o < 64; o <<= 1) s += __shfl_xor(s, o);
    if (lane == 0) an[row] = s;
    // fp8 e4m3 pack (scaled)
    int w0 = __builtin_amdgcn_cvt_pk_fp8_f32(v0.x * FP8_SCALE, v0.y * FP8_SCALE, 0, 0);
    w0     = __builtin_amdgcn_cvt_pk_fp8_f32(v0.z * FP8_SCALE, v0.w * FP8_SCALE, w0, 1);
    int w1 = __builtin_amdgcn_cvt_pk_fp8_f32(v1.x * FP8_SCALE, v1.y * FP8_SCALE, 0, 0);
    w1     = __builtin_amdgcn_cvt_pk_fp8_f32(v1.z * FP8_SCALE, v1.w * FP8_SCALE, w1, 1);
    *(int2*)&lrow[rl * 528 + lane * 8] = make_int2(w0, w1);
#pragma unroll
    for (int c = 0; c < 7; ++c) {
      const float4* w4 = (const float4*)(W + c * D_DIM);
      float4 q0 = w4[lane * 2], q1 = w4[lane * 2 + 1];
      float p = v0.x * q0.x + v0.y * q0.y + v0.z * q0.z + v0.w * q0.w +
                v1.x * q1.x + v1.y * q1.y + v1.z * q1.z + v1.w * q1.w;
#pragma unroll
      for (int o = 1; o < 64; o <<= 1) p += __shfl_xor(p, o);
      if (lane == 0) logits[row * 7 + c] = p;
    }
  }
  __syncthreads();
  // packed write-out: 1024 16B-chunks/block, coalesced
  int4* outp = (int4*)f8p + (size_t)blockIdx.x * 1024;
#pragma unroll
  for (int pi = 0; pi < 4; ++pi) {
    int c = pi * 256 + t;
    int gl = c >> 9, p = (c >> 6) & 7, l = c & 63;
    int q = l >> 4, sIdx = l & 15;
    int row = gl * 16 + sIdx;
    int2 lo = *(const int2*)&lrow[row * 528 + p * 64 + q * 8];
    int2 hi = *(const int2*)&lrow[row * 528 + p * 64 + 32 + q * 8];
    outp[c] = make_int4(lo.x, lo.y, hi.x, hi.y);
  }
}

// K1: fused Gram + exp reductions, barrier-free register-direct fp8 MFMA.
// 128x128 tile, 2x2 waves of 64x64; per p-step (64 k): 8 coalesced 1KB
// wave-loads + 32 MFMA, register double-buffered. XCD-aware grid +
// atomic-free rowsum partials. Stats blocks appended.
__global__ __launch_bounds__(256, 2) void k_gram(const char* __restrict__ f8p,
                                                 const float* __restrict__ an,
                                                 const float* __restrict__ logits,
                                                 float* __restrict__ S,
                                                 float* __restrict__ rs_part,
                                                 float* __restrict__ S1,
                                                 float* __restrict__ S2) {
  int unit = blockIdx.x >> 3, xcd = blockIdx.x & 7;
  int t = threadIdx.x, lane = t & 63, wave = t >> 6;

  if (unit >= 311) {  // batch-norm stats partials
    int sidx = (unit - 311) * 8 + xcd;  // 0..55
    int c = sidx >> 3, chunk = sidx & 7;
    int r0 = chunk * 1792;
    float s1 = 0.f, s2 = 0.f;
    for (int j = t; j < 1792; j += 256) {
      float v = logits[(r0 + j) * 7 + c];
      s1 += v;
      s2 += v * v;
    }
#pragma unroll
    for (int o = 1; o < 64; o <<= 1) {
      s1 += __shfl_xor(s1, o);
      s2 += __shfl_xor(s2, o);
    }
    __shared__ float r1_[4], r2_[4];
    if (lane == 0) { r1_[wave] = s1; r2_[wave] = s2; }
    __syncthreads();
    if (t == 0) {
      atomicAdd(&S1[c], r1_[0] + r1_[1] + r1_[2] + r1_[3]);
      atomicAdd(&S2[c], r2_[0] + r2_[1] + r2_[2] + r2_[3]);
    }
    return;
  }

  int c1, c2, TI, TJ, Sidx;
  bool self;
  if (xcd < 7 && unit < 136) {
    int tj = 0, t2 = unit;
    while (t2 > tj) { t2 -= (tj + 1); ++tj; }  // idx = tj*(tj+1)/2 + ti, ti<=tj
    TI = t2; TJ = tj;
    c1 = xcd; c2 = xcd; Sidx = xcd; self = true;
  } else {
    int e = (xcd < 7) ? (xcd * 175 + unit - 136) : (1225 + unit);
    int p = e >> 8;
    int tl = e & 255;
    TJ = tl >> 4; TI = tl & 15;
    c1 = p + 1; c2 = 0; Sidx = 7 + p; self = false;
  }
  bool diag = self && (TI == TJ);
  bool off  = self && (TI < TJ);
  int rowA0 = c1 * M_CLS + TI * 128;
  int rowB0 = c2 * M_CLS + TJ * 128;

  int wr = wave >> 1, wc = wave & 1;  // 2x2 waves of 64x64
  int q = lane >> 4, s = lane & 15;

  // fragment 16B-unit offsets: group g at g*512, + p*64 + lane
  const longlong2* fl = (const longlong2*)f8p;
  int gA = (rowA0 >> 4) + wr * 4;
  int gB = (rowB0 >> 4) + wc * 4;
  int oA[4], oB[4];
#pragma unroll
  for (int m = 0; m < 4; ++m) {
    oA[m] = (gA + m) * 512 + lane;
    oB[m] = (gB + m) * 512 + lane;  // diag: == oA (L1-hit)
  }

  f32x4 acc[4][4];
#pragma unroll
  for (int i = 0; i < 4; ++i)
#pragma unroll
    for (int j = 0; j < 4; ++j)
      acc[i][j] = (f32x4){0.f, 0.f, 0.f, 0.f};

  longlong2 fa[2][4], fbv[2][4];
#define LD(buf_, p_)                                   \
  do {                                                 \
    _Pragma("unroll") for (int m = 0; m < 4; ++m) {    \
      fa[buf_][m]  = fl[oA[m] + (p_) * 64];            \
      fbv[buf_][m] = fl[oB[m] + (p_) * 64];            \
    }                                                  \
  } while (0)

  LD(0, 0);
#pragma unroll
  for (int p = 0; p < 8; ++p) {
    int cur = p & 1;
    if (p < 7) LD(cur ^ 1, p + 1);
#pragma unroll
    for (int mi = 0; mi < 4; ++mi)
#pragma unroll
      for (int mj = 0; mj < 4; ++mj)
        acc[mi][mj] = __builtin_amdgcn_mfma_f32_16x16x32_fp8_fp8(
            fa[cur][mi].x, fbv[cur][mj].x, acc[mi][mj], 0, 0, 0);
#pragma unroll
    for (int mi = 0; mi < 4; ++mi)
#pragma unroll
      for (int mj = 0; mj < 4; ++mj)
        acc[mi][mj] = __builtin_amdgcn_mfma_f32_16x16x32_fp8_fp8(
            fa[cur][mi].y, fbv[cur][mj].y, acc[mi][mj], 0, 0, 0);
  }
#undef LD

  // row norms into registers (fp32-exact, L2-hot)
  float anA[4][4], anB[4];
#pragma unroll
  for (int mi = 0; mi < 4; ++mi)
#pragma unroll
    for (int rg = 0; rg < 4; ++rg)
      anA[mi][rg] = an[rowA0 + wr * 64 + mi * 16 + q * 4 + rg];
#pragma unroll
  for (int mj = 0; mj < 4; ++mj)
    anB[mj] = an[rowB0 + wc * 64 + mj * 16 + s];

  // Epilogue. C/D layout (16x16x32, dtype-independent): col=lane&15,
  // row=(lane>>4)*4+reg. 5-kernel sum via exp-squaring from e1=exp(-0.05*d2).
  float blockAcc = 0.f;
  float colAcc[4] = {0.f, 0.f, 0.f, 0.f};
  float* dirP = rs_part + (size_t)(TJ * 2 + wc) * 14336 + rowA0;
#pragma unroll
  for (int mi = 0; mi < 4; ++mi) {
#pragma unroll
    for (int rg = 0; rg < 4; ++rg) {
      int rl = wr * 64 + mi * 16 + q * 4 + rg;
      float aA = anA[mi][rg];
      float rowAcc = 0.f;
#pragma unroll
      for (int mj = 0; mj < 4; ++mj) {
        int cl = wc * 64 + mj * 16 + s;
        float g = acc[mi][mj][rg];
        float d2 = fmaxf(aA + anB[mj] - g * INV_2S2, 0.f);
        if (diag && rl == cl) d2 = 0.f;  // exact diagonal
        float e1 = __expf(-0.05f * d2);
        float e2 = e1 * e1, e4 = e2 * e2, e8 = e4 * e4, e16 = e8 * e8;
        blockAcc += e1 + e2 + e4 + e8 + e16;
        if (self) {
          float ek = __expf(-12.5f * d2);  // KDE: 1/(2*0.2^2)
          rowAcc += ek;
          if (off) colAcc[mj] += ek;
        }
      }
      if (self) {
        rowAcc += __shfl_xor(rowAcc, 1);
        rowAcc += __shfl_xor(rowAcc, 2);
        rowAcc += __shfl_xor(rowAcc, 4);
        rowAcc += __shfl_xor(rowAcc, 8);
        if (s == 0) dirP[rl] = rowAcc;
      }
    }
  }
  if (off) {
    float* mirP = rs_part + (size_t)(TI * 2 + wr) * 14336 + rowB0;
#pragma unroll
    for (int mj = 0; mj < 4; ++mj) {
      float v = colAcc[mj];
      v += __shfl_xor(v, 16);
      v += __shfl_xor(v, 32);
      if (q == 0) mirP[wc * 64 + mj * 16 + s] = v;
    }
    blockAcc *= 2.f;  // mirror tile counted once
  }
#pragma unroll
  for (int o = 1; o < 64; o <<= 1) blockAcc += __shfl_xor(blockAcc, o);
  if (lane == 0) atomicAdd(&S[Sidx], blockAcc);
}

// K2: bnout (blocks 0..391) + per-class KDE weight & affinity term (392..398).
__global__ __launch_bounds__(256) void k_final(const float* __restrict__ logits,
                                               const float* __restrict__ S1,
                                               const float* __restrict__ S2,
                                               const float* __restrict__ gamma,
                                               const float* __restrict__ beta,
                                               const float* __restrict__ rs_part,
                                               const float* __restrict__ S,
                                               float* __restrict__ out) {
  int b = blockIdx.x, t = threadIdx.x;
  if (b < 392) {
    int idx = b * 256 + t;  // 392*256 = 100352 exactly
    int row = idx / 7;
    int c = idx - row * 7;
    float mu = S1[c] * (1.f / 14336.f);
    float var = S2[c] * (1.f / 14336.f) - mu * mu;
    out[idx] = gamma[c] * (logits[idx] - mu) * rsqrtf(var + 1e-5f) + beta[c];
    return;
  }
  int c = b - 392;
  // log_norm = -256*ln(2*pi*0.04) - ln(2048)
  const float LOG_NORM = 345.9110632f;
  float v = 0.f;
  for (int i = t; i < M_CLS; i += 256) {
    int row = c * M_CLS + i;
    float rsum = 0.f;
#pragma unroll
    for (int jj = 0; jj < 32; ++jj) rsum += rs_part[jj * 14336 + row];
    v += 1.f / (logf(rsum) + LOG_NORM);
  }
#pragma unroll
  for (int o = 1; o < 64; o <<= 1) v += __shfl_xor(v, o);
  __shared__ float r[4];
  if ((t & 63) == 0) r[t >> 6] = v;
  __syncthreads();
  if (t == 0) {
    float w = 1.f / ((r[0] + r[1] + r[2] + r[3]) + 1e-5f);
    const float inv_m2 = 1.0f / ((float)M_CLS * (float)M_CLS);
    float Ssrc = S[c];
    float Stgt = (c > 0) ? S[0] : S[1];
    float X    = (c > 0) ? S[6 + c] : S[7];  // cross Sidx 7+p is (p+1,0); X01==X10
    float mmd = (Ssrc + Stgt - 2.f * X) * inv_m2;
    atomicAdd(&out[100352], -mmd * w);
  }
}

extern "C" void kernel_launch(void* const* d_in, const int* in_sizes, int n_in,
                              void* d_out, int out_size, void* d_ws, size_t ws_size,
                              hipStream_t stream) {
  const float* fea   = (const float*)d_in[0];
  const float* W_fc  = (const float*)d_in[1];
  const float* gamma = (const float*)d_in[2];
  const float* beta  = (const float*)d_in[3];
  float* out = (float*)d_out;

  char* ws = (char*)d_ws;
  char* f8p = ws;                                // packed fp8 fea: 7,340,032 B
  float* fbase   = (float*)(ws + 7340032);
  float* an      = fbase;                        // 14336
  float* logits  = fbase + 14336;                // 100352
  float* zb      = fbase + 114688;               // 64-float zero block
  float* S1      = zb;                           //   [0..6]
  float* S2      = zb + 7;                       //   [7..13]
  float* S       = zb + 16;                      //   [16..28] (13 used)
  float* rs_part = fbase + 114752;               // 32*14336 = 458752 (fully written)

  k_prep <<<448,  256, 0, stream>>>(fea, W_fc, f8p, an, logits, zb, out + 100352);
  k_gram <<<2544, 256, 0, stream>>>(f8p, an, logits, S, rs_part, S1, S2);
  k_final<<<399,  256, 0, stream>>>(logits, S1, S2, gamma, beta, rs_part, S, out);
}

// Round 10
// 246.435 us; speedup vs baseline: 1.3898x; 1.0303x over previous
//
#include <hip/hip_runtime.h>

#define B_ROWS 14336
#define D_DIM  512
#define C_CLS  7
#define M_CLS  2048

typedef __attribute__((ext_vector_type(4))) float f32x4;

// fp8 scale: fea*64 -> sigma~3.2 in e4m3 range; Gram scaled by 4096
#define FP8_SCALE 64.0f
#define INV_2S2   (2.0f / 4096.0f)

// K0: fea->fp8 FRAGMENT-PACKED + row norms (fp32-exact) + logits + zeroing.
// Packed 16B units: flat = g*512 + p*64 + lane, g=row/16, p=k/64, lane=q*16+s.
// Lane's 16B = [k = p*64+q*8 .. +7][k = p*64+32+q*8 .. +7] of row s.
// 896 blocks x 16 rows (exactly one packed group) -> 4 rows/wave.
__global__ __launch_bounds__(256) void k_prep(const float* __restrict__ fea,
                                              const float* __restrict__ W,
                                              char* __restrict__ f8p,
                                              float* __restrict__ an,
                                              float* __restrict__ logits,
                                              float* __restrict__ zb,   // 64 floats: S1,S2,S
                                              float* __restrict__ aff_out) {
  int t = threadIdx.x, wave = t >> 6, lane = t & 63;
  if (blockIdx.x == 0) {
    if (t < 64) zb[t] = 0.f;
    if (t == 64) aff_out[0] = 0.f;
  }
  __shared__ char lrow[16 * 528];  // 16 rows x 512B fp8 (+16 pad)

  int r0 = blockIdx.x * 16;
#pragma unroll
  for (int k = 0; k < 4; ++k) {
    int rl = wave * 4 + k;
    int row = r0 + rl;
    const float4* fr4 = (const float4*)(fea + (size_t)row * D_DIM);
    float4 v0 = fr4[lane * 2], v1 = fr4[lane * 2 + 1];
    float s = v0.x * v0.x + v0.y * v0.y + v0.z * v0.z + v0.w * v0.w +
              v1.x * v1.x + v1.y * v1.y + v1.z * v1.z + v1.w * v1.w;
#pragma unroll
    for (int o = 1; o < 64; o <<= 1) s += __shfl_xor(s, o);
    if (lane == 0) an[row] = s;
    // fp8 e4m3 pack (scaled)
    int w0 = __builtin_amdgcn_cvt_pk_fp8_f32(v0.x * FP8_SCALE, v0.y * FP8_SCALE, 0, 0);
    w0     = __builtin_amdgcn_cvt_pk_fp8_f32(v0.z * FP8_SCALE, v0.w * FP8_SCALE, w0, 1);
    int w1 = __builtin_amdgcn_cvt_pk_fp8_f32(v1.x * FP8_SCALE, v1.y * FP8_SCALE, 0, 0);
    w1     = __builtin_amdgcn_cvt_pk_fp8_f32(v1.z * FP8_SCALE, v1.w * FP8_SCALE, w1, 1);
    *(int2*)&lrow[rl * 528 + lane * 8] = make_int2(w0, w1);
#pragma unroll
    for (int c = 0; c < 7; ++c) {
      const float4* w4 = (const float4*)(W + c * D_DIM);
      float4 q0 = w4[lane * 2], q1 = w4[lane * 2 + 1];
      float p = v0.x * q0.x + v0.y * q0.y + v0.z * q0.z + v0.w * q0.w +
                v1.x * q1.x + v1.y * q1.y + v1.z * q1.z + v1.w * q1.w;
#pragma unroll
      for (int o = 1; o < 64; o <<= 1) p += __shfl_xor(p, o);
      if (lane == 0) logits[row * 7 + c] = p;
    }
  }
  __syncthreads();
  // packed write-out: 512 16B-chunks/block (one group), coalesced
  int4* outp = (int4*)f8p + (size_t)blockIdx.x * 512;
#pragma unroll
  for (int pi = 0; pi < 2; ++pi) {
    int c = pi * 256 + t;
    int p = c >> 6, l = c & 63;
    int q = l >> 4, sIdx = l & 15;
    int2 lo = *(const int2*)&lrow[sIdx * 528 + p * 64 + q * 8];
    int2 hi = *(const int2*)&lrow[sIdx * 528 + p * 64 + 32 + q * 8];
    outp[c] = make_int4(lo.x, lo.y, hi.x, hi.y);
  }
}

// K1: fused Gram + exp reductions, barrier-free register-direct fp8 MFMA.
// 128x128 tile, 2x2 waves of 64x64; per p-step (64 k): 8 coalesced 1KB
// wave-loads + 32 MFMA, SINGLE-buffered fragments (32 regs) so total regs
// fit 4 waves/SIMD (__launch_bounds__(256,4)) — occupancy over prefetch depth.
// XCD-aware grid + atomic-free rowsum partials. Stats blocks appended.
__global__ __launch_bounds__(256, 4) void k_gram(const char* __restrict__ f8p,
                                                 const float* __restrict__ an,
                                                 const float* __restrict__ logits,
                                                 float* __restrict__ S,
                                                 float* __restrict__ rs_part,
                                                 float* __restrict__ S1,
                                                 float* __restrict__ S2) {
  int unit = blockIdx.x >> 3, xcd = blockIdx.x & 7;
  int t = threadIdx.x, lane = t & 63, wave = t >> 6;

  if (unit >= 311) {  // batch-norm stats partials
    int sidx = (unit - 311) * 8 + xcd;  // 0..55
    int c = sidx >> 3, chunk = sidx & 7;
    int r0 = chunk * 1792;
    float s1 = 0.f, s2 = 0.f;
    for (int j = t; j < 1792; j += 256) {
      float v = logits[(r0 + j) * 7 + c];
      s1 += v;
      s2 += v * v;
    }
#pragma unroll
    for (int o = 1; o < 64; o <<= 1) {
      s1 += __shfl_xor(s1, o);
      s2 += __shfl_xor(s2, o);
    }
    __shared__ float r1_[4], r2_[4];
    if (lane == 0) { r1_[wave] = s1; r2_[wave] = s2; }
    __syncthreads();
    if (t == 0) {
      atomicAdd(&S1[c], r1_[0] + r1_[1] + r1_[2] + r1_[3]);
      atomicAdd(&S2[c], r2_[0] + r2_[1] + r2_[2] + r2_[3]);
    }
    return;
  }

  int c1, c2, TI, TJ, Sidx;
  bool self;
  if (xcd < 7 && unit < 136) {
    int tj = 0, t2 = unit;
    while (t2 > tj) { t2 -= (tj + 1); ++tj; }  // idx = tj*(tj+1)/2 + ti, ti<=tj
    TI = t2; TJ = tj;
    c1 = xcd; c2 = xcd; Sidx = xcd; self = true;
  } else {
    int e = (xcd < 7) ? (xcd * 175 + unit - 136) : (1225 + unit);
    int p = e >> 8;
    int tl = e & 255;
    TJ = tl >> 4; TI = tl & 15;
    c1 = p + 1; c2 = 0; Sidx = 7 + p; self = false;
  }
  bool diag = self && (TI == TJ);
  bool off  = self && (TI < TJ);
  int rowA0 = c1 * M_CLS + TI * 128;
  int rowB0 = c2 * M_CLS + TJ * 128;

  int wr = wave >> 1, wc = wave & 1;  // 2x2 waves of 64x64
  int q = lane >> 4, s = lane & 15;

  // fragment 16B-unit offsets: group g at g*512, + p*64 + lane
  const longlong2* fl = (const longlong2*)f8p;
  int gA = (rowA0 >> 4) + wr * 4;
  int gB = (rowB0 >> 4) + wc * 4;
  int oA[4], oB[4];
#pragma unroll
  for (int m = 0; m < 4; ++m) {
    oA[m] = (gA + m) * 512 + lane;
    oB[m] = (gB + m) * 512 + lane;  // diag: == oA (L1-hit)
  }

  f32x4 acc[4][4];
#pragma unroll
  for (int i = 0; i < 4; ++i)
#pragma unroll
    for (int j = 0; j < 4; ++j)
      acc[i][j] = (f32x4){0.f, 0.f, 0.f, 0.f};

  longlong2 fa[4], fbv[4];
#pragma unroll
  for (int p = 0; p < 8; ++p) {
#pragma unroll
    for (int m = 0; m < 4; ++m) {
      fa[m]  = fl[oA[m] + p * 64];
      fbv[m] = fl[oB[m] + p * 64];
    }
#pragma unroll
    for (int mi = 0; mi < 4; ++mi)
#pragma unroll
      for (int mj = 0; mj < 4; ++mj)
        acc[mi][mj] = __builtin_amdgcn_mfma_f32_16x16x32_fp8_fp8(
            fa[mi].x, fbv[mj].x, acc[mi][mj], 0, 0, 0);
#pragma unroll
    for (int mi = 0; mi < 4; ++mi)
#pragma unroll
      for (int mj = 0; mj < 4; ++mj)
        acc[mi][mj] = __builtin_amdgcn_mfma_f32_16x16x32_fp8_fp8(
            fa[mi].y, fbv[mj].y, acc[mi][mj], 0, 0, 0);
  }

  // row norms into registers (fp32-exact, L2-hot)
  float anA[4][4], anB[4];
#pragma unroll
  for (int mi = 0; mi < 4; ++mi)
#pragma unroll
    for (int rg = 0; rg < 4; ++rg)
      anA[mi][rg] = an[rowA0 + wr * 64 + mi * 16 + q * 4 + rg];
#pragma unroll
  for (int mj = 0; mj < 4; ++mj)
    anB[mj] = an[rowB0 + wc * 64 + mj * 16 + s];

  // Epilogue. C/D layout (16x16x32, dtype-independent): col=lane&15,
  // row=(lane>>4)*4+reg. 5-kernel sum via exp-squaring from e1=exp(-0.05*d2).
  float blockAcc = 0.f;
  float colAcc[4] = {0.f, 0.f, 0.f, 0.f};
  float* dirP = rs_part + (size_t)(TJ * 2 + wc) * 14336 + rowA0;
#pragma unroll
  for (int mi = 0; mi < 4; ++mi) {
#pragma unroll
    for (int rg = 0; rg < 4; ++rg) {
      int rl = wr * 64 + mi * 16 + q * 4 + rg;
      float aA = anA[mi][rg];
      float rowAcc = 0.f;
#pragma unroll
      for (int mj = 0; mj < 4; ++mj) {
        int cl = wc * 64 + mj * 16 + s;
        float g = acc[mi][mj][rg];
        float d2 = fmaxf(aA + anB[mj] - g * INV_2S2, 0.f);
        if (diag && rl == cl) d2 = 0.f;  // exact diagonal
        float e1 = __expf(-0.05f * d2);
        float e2 = e1 * e1, e4 = e2 * e2, e8 = e4 * e4, e16 = e8 * e8;
        blockAcc += e1 + e2 + e4 + e8 + e16;
        if (self) {
          float ek = __expf(-12.5f * d2);  // KDE: 1/(2*0.2^2)
          rowAcc += ek;
          if (off) colAcc[mj] += ek;
        }
      }
      if (self) {
        rowAcc += __shfl_xor(rowAcc, 1);
        rowAcc += __shfl_xor(rowAcc, 2);
        rowAcc += __shfl_xor(rowAcc, 4);
        rowAcc += __shfl_xor(rowAcc, 8);
        if (s == 0) dirP[rl] = rowAcc;
      }
    }
  }
  if (off) {
    float* mirP = rs_part + (size_t)(TI * 2 + wr) * 14336 + rowB0;
#pragma unroll
    for (int mj = 0; mj < 4; ++mj) {
      float v = colAcc[mj];
      v += __shfl_xor(v, 16);
      v += __shfl_xor(v, 32);
      if (q == 0) mirP[wc * 64 + mj * 16 + s] = v;
    }
    blockAcc *= 2.f;  // mirror tile counted once
  }
#pragma unroll
  for (int o = 1; o < 64; o <<= 1) blockAcc += __shfl_xor(blockAcc, o);
  if (lane == 0) atomicAdd(&S[Sidx], blockAcc);
}

// K2: bnout (blocks 0..391) + per-class KDE weight & affinity term (392..398).
__global__ __launch_bounds__(256) void k_final(const float* __restrict__ logits,
                                               const float* __restrict__ S1,
                                               const float* __restrict__ S2,
                                               const float* __restrict__ gamma,
                                               const float* __restrict__ beta,
                                               const float* __restrict__ rs_part,
                                               const float* __restrict__ S,
                                               float* __restrict__ out) {
  int b = blockIdx.x, t = threadIdx.x;
  if (b < 392) {
    int idx = b * 256 + t;  // 392*256 = 100352 exactly
    int row = idx / 7;
    int c = idx - row * 7;
    float mu = S1[c] * (1.f / 14336.f);
    float var = S2[c] * (1.f / 14336.f) - mu * mu;
    out[idx] = gamma[c] * (logits[idx] - mu) * rsqrtf(var + 1e-5f) + beta[c];
    return;
  }
  int c = b - 392;
  // log_norm = -256*ln(2*pi*0.04) - ln(2048)
  const float LOG_NORM = 345.9110632f;
  float v = 0.f;
  for (int i = t; i < M_CLS; i += 256) {
    int row = c * M_CLS + i;
    float rsum = 0.f;
#pragma unroll
    for (int jj = 0; jj < 32; ++jj) rsum += rs_part[jj * 14336 + row];
    v += 1.f / (logf(rsum) + LOG_NORM);
  }
#pragma unroll
  for (int o = 1; o < 64; o <<= 1) v += __shfl_xor(v, o);
  __shared__ float r[4];
  if ((t & 63) == 0) r[t >> 6] = v;
  __syncthreads();
  if (t == 0) {
    float w = 1.f / ((r[0] + r[1] + r[2] + r[3]) + 1e-5f);
    const float inv_m2 = 1.0f / ((float)M_CLS * (float)M_CLS);
    float Ssrc = S[c];
    float Stgt = (c > 0) ? S[0] : S[1];
    float X    = (c > 0) ? S[6 + c] : S[7];  // cross Sidx 7+p is (p+1,0); X01==X10
    float mmd = (Ssrc + Stgt - 2.f * X) * inv_m2;
    atomicAdd(&out[100352], -mmd * w);
  }
}

extern "C" void kernel_launch(void* const* d_in, const int* in_sizes, int n_in,
                              void* d_out, int out_size, void* d_ws, size_t ws_size,
                              hipStream_t stream) {
  const float* fea   = (const float*)d_in[0];
  const float* W_fc  = (const float*)d_in[1];
  const float* gamma = (const float*)d_in[2];
  const float* beta  = (const float*)d_in[3];
  float* out = (float*)d_out;

  char* ws = (char*)d_ws;
  char* f8p = ws;                                // packed fp8 fea: 7,340,032 B
  float* fbase   = (float*)(ws + 7340032);
  float* an      = fbase;                        // 14336
  float* logits  = fbase + 14336;                // 100352
  float* zb      = fbase + 114688;               // 64-float zero block
  float* S1      = zb;                           //   [0..6]
  float* S2      = zb + 7;                       //   [7..13]
  float* S       = zb + 16;                      //   [16..28] (13 used)
  float* rs_part = fbase + 114752;               // 32*14336 = 458752 (fully written)

  k_prep <<<896,  256, 0, stream>>>(fea, W_fc, f8p, an, logits, zb, out + 100352);
  k_gram <<<2544, 256, 0, stream>>>(f8p, an, logits, S, rs_part, S1, S2);
  k_final<<<399,  256, 0, stream>>>(logits, S1, S2, gamma, beta, rs_part, S, out);
}